// Round 3
// baseline (152.766 us; speedup 1.0000x reference)
//
#include <hip/hip_runtime.h>
#include <hip/hip_cooperative_groups.h>

namespace cg = cooperative_groups;

// Problem constants
#define LSEQ 256   // sequence length (i, j range)
#define INC  256   // in_channels
#define HID  32    // hidden_dim
#define OUTC 32    // out_channels
#define DE   1024  // HID*HID (LayerNorm width)
#define EPSV 1e-5f

// aPad layout: a[i][d] at aPad[(i>>3)*ASTR + d*8 + (i&7)]; 260%32==4 keeps the
// phase-2 float4 reads across iT lanes on disjoint 4-bank groups (conflict-free).
#define ASTR 260
// tPad: T[d][o] at tPad[d*TSTR + o]; 36%32==4 -> disjoint 4-bank groups across oT.
#define TSTR 36
// gamma: gLp[d*33 + e]; bank (d+e)%32 -> phase-1 reads across d are conflict-free.
#define GSTR 33

__global__ __launch_bounds__(256) void fused_all(
    const float* __restrict__ x, const float* __restrict__ W1, const float* __restrict__ b1,
    const float* __restrict__ gamma, const float* __restrict__ beta,
    const float* __restrict__ W2, const float* __restrict__ b2,
    float* __restrict__ aG, float* __restrict__ SG, float* __restrict__ QG,
    float* __restrict__ GWG, float* __restrict__ CG,
    float* __restrict__ out)
{
    const int b = blockIdx.x, t = threadIdx.x;

    __shared__ float aPad[32 * ASTR];   // 33.3 KB
    __shared__ float tPad[32 * TSTR];   // 4.6 KB
    __shared__ float gLp[32 * GSTR];    // 4.2 KB
    __shared__ float sL[LSEQ];
    __shared__ float qL[LSEQ];
    __shared__ float gwL[OUTC], cL[OUTC];
    __shared__ float shRed[256];
    __shared__ float shRed2[256];
    __shared__ float shRow[HID];

    // =======================================================================
    // Phase A: block b computes a-row b (+ S_b, Q_b); block 0 also GW, C
    // =======================================================================
    {
        const int d = t & 31, ch = t >> 5;     // 8 chunks x 32 c each
        const float* xr = x + b * INC + ch * 32;
        const float* w  = W1 + (ch * 32) * HID + d;
        float p = 0.f;
        #pragma unroll
        for (int k = 0; k < 32; ++k)
            p = fmaf(xr[k], w[k * HID], p);    // xr[k]: broadcast; w: coalesced over d
        shRed[t] = p;
        __syncthreads();
        if (t < 32) {
            float v = b1[t];
            #pragma unroll
            for (int c2 = 0; c2 < 8; ++c2) v += shRed[t + 32 * c2];
            aG[b * HID + t] = v;
            shRow[t] = v;
        }
        __syncthreads();
        if (t == 0) {
            float s = 0.f, q = 0.f;
            #pragma unroll
            for (int d2 = 0; d2 < 32; ++d2) { s += shRow[d2]; q = fmaf(shRow[d2], shRow[d2], q); }
            SG[b] = s;
            QG[b] = q;
        }
        if (b == 0) {
            const int o = t & 31, ck = t >> 5; // 8 chunks x 128 de each
            float gw = 0.f, bw = 0.f;
            for (int k = 0; k < 128; ++k) {
                const int de = ck * 128 + k;
                const float wv = W2[de * OUTC + o];   // coalesced over o
                gw = fmaf(gamma[de], wv, gw);
                bw = fmaf(beta[de],  wv, bw);
            }
            __syncthreads();
            shRed[t] = gw; shRed2[t] = bw;
            __syncthreads();
            if (t < 32) {
                float g = 0.f, bb = 0.f;
                #pragma unroll
                for (int c2 = 0; c2 < 8; ++c2) { g += shRed[c2 * 32 + t]; bb += shRed2[c2 * 32 + t]; }
                GWG[t] = g;
                CG[t]  = bb + b2[t];
            }
        }
    }

    __threadfence();          // device-scope release of aG/SG/QG/GWG/CG
    cg::this_grid().sync();   // all 256 blocks co-resident (1 block/CU)

    // =======================================================================
    // Phase B: per-j fused T + GEMM + LN epilogue (j = blockIdx.x)
    // =======================================================================
    const int j = b;

    // ---- stage ----
    {   // thread t owns row i=t of a: 8 float4 global reads, scatter to aPad
        const float4* ar4 = (const float4*)(aG + t * HID);
        const int base = (t >> 3) * ASTR + (t & 7);
        #pragma unroll
        for (int c = 0; c < 8; ++c) {
            const float4 v = ar4[c];
            const int d = c * 4;
            aPad[base + (d + 0) * 8] = v.x;
            aPad[base + (d + 1) * 8] = v.y;
            aPad[base + (d + 2) * 8] = v.z;
            aPad[base + (d + 3) * 8] = v.w;
        }
    }
    #pragma unroll
    for (int k = t; k < DE; k += 256) gLp[(k >> 5) * GSTR + (k & 31)] = gamma[k];
    sL[t] = SG[t];
    qL[t] = QG[t];
    if (t < OUTC) { gwL[t] = GWG[t]; cL[t] = CG[t]; }
    __syncthreads();

    // ---- T_j[d][o] = sum_e a[j,e]*gamma[d,e]*W2[(d*32+e)*32+o] ----
    {
        const int d = t >> 3, o0 = (t & 7) * 4;
        const int jb = (j >> 3) * ASTR + (j & 7);
        float4 acc = {0.f, 0.f, 0.f, 0.f};
        #pragma unroll
        for (int e = 0; e < 32; ++e) {
            const float g = gLp[d * GSTR + e] * aPad[jb + e * 8];
            const float4 w = *(const float4*)(W2 + (d * 32 + e) * OUTC + o0);
            acc.x = fmaf(g, w.x, acc.x);
            acc.y = fmaf(g, w.y, acc.y);
            acc.z = fmaf(g, w.z, acc.z);
            acc.w = fmaf(g, w.w, acc.w);
        }
        *(float4*)(tPad + d * TSTR + o0) = acc;
    }
    __syncthreads();

    // ---- reg-tiled GEMM: thread (iT=t>>3, oT=t&7) owns 8i x 4o tile ----
    const int iT = t >> 3, oT = t & 7;
    const int abase = iT * ASTR;
    float acc[8][4];
    #pragma unroll
    for (int m = 0; m < 8; ++m)
        #pragma unroll
        for (int k = 0; k < 4; ++k) acc[m][k] = 0.f;

    #pragma unroll
    for (int d = 0; d < 32; ++d) {
        const float4 a0 = *(const float4*)(aPad + abase + d * 8);
        const float4 a1 = *(const float4*)(aPad + abase + d * 8 + 4);
        const float4 tf = *(const float4*)(tPad + d * TSTR + oT * 4);
        const float am[8] = {a0.x, a0.y, a0.z, a0.w, a1.x, a1.y, a1.z, a1.w};
        const float tk[4] = {tf.x, tf.y, tf.z, tf.w};
        #pragma unroll
        for (int m = 0; m < 8; ++m)
            #pragma unroll
            for (int k = 0; k < 4; ++k)
                acc[m][k] = fmaf(am[m], tk[k], acc[m][k]);
    }

    const float Sj = sL[j], Qj = qL[j];
    const float gw0 = gwL[oT * 4 + 0], gw1 = gwL[oT * 4 + 1];
    const float gw2 = gwL[oT * 4 + 2], gw3 = gwL[oT * 4 + 3];
    const float c0 = cL[oT * 4 + 0], c1 = cL[oT * 4 + 1];
    const float c2 = cL[oT * 4 + 2], c3 = cL[oT * 4 + 3];

    #pragma unroll
    for (int m = 0; m < 8; ++m) {
        const int i = iT * 8 + m;
        const float Si = sL[i], Qi = qL[i];
        const float mu  = Si * Sj * (1.0f / 1024.0f);
        const float ex2 = Qi * Qj * (1.0f / 1024.0f);
        const float var = ex2 - mu * mu;
        const float r   = rsqrtf(var + EPSV);
        float4 o4;
        o4.x = fmaf(r, acc[m][0] - mu * gw0, c0);
        o4.y = fmaf(r, acc[m][1] - mu * gw1, c1);
        o4.z = fmaf(r, acc[m][2] - mu * gw2, c2);
        o4.w = fmaf(r, acc[m][3] - mu * gw3, c3);
        // 8 consecutive lanes (oT=0..7) cover one full 128 B row (i,j,:)
        *(float4*)(out + (i * LSEQ + j) * OUTC + oT * 4) = o4;
    }
}

// ---------------------------------------------------------------------------
extern "C" void kernel_launch(void* const* d_in, const int* in_sizes, int n_in,
                              void* d_out, int out_size, void* d_ws, size_t ws_size,
                              hipStream_t stream)
{
    const float* x     = (const float*)d_in[0];
    const float* W1    = (const float*)d_in[1];
    const float* b1    = (const float*)d_in[2];
    const float* gamma = (const float*)d_in[3];
    const float* beta  = (const float*)d_in[4];
    const float* W2    = (const float*)d_in[5];
    const float* b2    = (const float*)d_in[6];
    float* out = (float*)d_out;

    // workspace layout (floats)
    float* ws = (float*)d_ws;
    float* a  = ws;            // 8192
    float* S  = ws + 8192;     // 256
    float* Q  = ws + 8448;     // 256
    float* GW = ws + 8704;     // 32
    float* C  = ws + 8736;     // 32

    void* args[] = {
        (void*)&x, (void*)&W1, (void*)&b1, (void*)&gamma, (void*)&beta,
        (void*)&W2, (void*)&b2,
        (void*)&a, (void*)&S, (void*)&Q, (void*)&GW, (void*)&C, (void*)&out
    };
    hipLaunchCooperativeKernel((const void*)fused_all, dim3(LSEQ), dim3(256),
                               args, 0, stream);
}

// Round 4
// 81.067 us; speedup vs baseline: 1.8844x; 1.8844x over previous
//
#include <hip/hip_runtime.h>

// Problem constants
#define LSEQ 256   // sequence length (i, j range)
#define INC  256   // in_channels
#define HID  32    // hidden_dim
#define OUTC 32    // out_channels
#define DE   1024  // HID*HID (LayerNorm width)
#define EPSV 1e-5f

// aPad layout (per i-half): a[i][d] at aPad[(il>>3)*ASTR + d*8 + (il&7)], il = i-128*ih.
// 260%32==4 -> phase-2 float4 reads across iT lanes hit disjoint 4-bank groups.
#define ASTR 260
// tPad: T[d][o] at tPad[d*TSTR + o]; 36%32==4 -> conflict-free across oT quads.
#define TSTR 36
// gamma: gLp[d*33 + e]; bank (d+e)%32 -> phase-1 reads across d are conflict-free.
#define GSTR 33

// ---------------------------------------------------------------------------
// k1: blocks 0..63 -> 4 rows each of a[i,d]=x[i,:]@W1[:,d]+b1[d], plus S_i,Q_i
//     block  64    -> GW[o]=sum_de gamma*W2 ; C[o]=sum_de beta*W2 + b2[o]
// ---------------------------------------------------------------------------
__global__ __launch_bounds__(256) void k1_a_stats(
    const float* __restrict__ x, const float* __restrict__ W1, const float* __restrict__ b1,
    const float* __restrict__ gamma, const float* __restrict__ beta,
    const float* __restrict__ W2, const float* __restrict__ b2,
    float* __restrict__ a, float* __restrict__ S, float* __restrict__ Q,
    float* __restrict__ GW, float* __restrict__ C)
{
    __shared__ float sh0[256];
    __shared__ float sh1[256];
    __shared__ float shA[128];
    __shared__ float shB[128];
    const int t = threadIdx.x;
    const int b = blockIdx.x;
    if (b < 64) {
        const int r = t >> 6;
        const int h = (t >> 5) & 1;
        const int d = t & 31;
        const int i = b * 4 + r;
        const float* xr = x + i * INC + h * 128;
        const float* w  = W1 + (h * 128) * HID + d;
        float p0 = 0.f, p1 = 0.f;                 // 2 independent chains
        #pragma unroll 8
        for (int k = 0; k < 64; ++k) {
            p0 = fmaf(xr[2 * k],     w[(2 * k) * HID],     p0);
            p1 = fmaf(xr[2 * k + 1], w[(2 * k + 1) * HID], p1);
        }
        sh0[t] = p0 + p1;
        __syncthreads();
        if (h == 0) {
            const float tot = sh0[t] + sh0[t + 32] + b1[d];
            a[i * HID + d] = tot;
            shA[r * 32 + d] = tot;
            shB[r * 32 + d] = tot * tot;
        }
        __syncthreads();
        if (t < 4) {
            float s = 0.f, q = 0.f;
            #pragma unroll
            for (int d2 = 0; d2 < 32; ++d2) { s += shA[t * 32 + d2]; q += shB[t * 32 + d2]; }
            S[b * 4 + t] = s;
            Q[b * 4 + t] = q;
        }
    } else {
        const int o = t & 31, chunk = t >> 5;     // 8 chunks x 128 de each
        float gw = 0.f, bw = 0.f;
        for (int k = 0; k < 128; ++k) {
            const int de = chunk * 128 + k;
            const float w = W2[de * OUTC + o];    // coalesced over o
            gw = fmaf(gamma[de], w, gw);
            bw = fmaf(beta[de],  w, bw);
        }
        sh0[t] = gw; sh1[t] = bw;
        __syncthreads();
        if (t < 32) {
            float g = 0.f, bb = 0.f;
            #pragma unroll
            for (int c2 = 0; c2 < 8; ++c2) { g += sh0[c2 * 32 + t]; bb += sh1[c2 * 32 + t]; }
            GW[t] = g;
            C[t]  = bb + b2[t];
        }
    }
}

// ---------------------------------------------------------------------------
// k2: fused per-(j, i-half) kernel. 512 blocks (2/CU), 256 threads.
//   j = blockIdx.x >> 1, ih = blockIdx.x & 1 -> i in [ih*128, ih*128+128)
//   phase 0: stage a-half (chunked-transposed), a[j,:], S, Q, GW, C, gamma
//   phase 1: T_j[d][o] = sum_e a[j,e]*gamma[d*32+e]*W2[(d*32+e)*32+o]
//   phase 2: reg-tiled GEMM: thread (iT=t>>3, oT=t&7) owns 4i x 4o tile
//            out[i,j,o] = r_ij*(sum_d a[i,d]*T[d,o] - mu_ij*GW[o]) + C[o]
// ---------------------------------------------------------------------------
__global__ __launch_bounds__(256) void k2_fused(
    const float* __restrict__ a, const float* __restrict__ S, const float* __restrict__ Q,
    const float* __restrict__ GW, const float* __restrict__ C,
    const float* __restrict__ gamma, const float* __restrict__ W2,
    float* __restrict__ out)
{
    const int j  = blockIdx.x >> 1;
    const int ih = blockIdx.x & 1;
    const int t  = threadIdx.x;

    __shared__ float aPad[16 * ASTR];   // 16.6 KB: this block's 128 i-rows
    __shared__ float ajL[HID];          // a[j,:]
    __shared__ float tPad[32 * TSTR];   // 4.6 KB
    __shared__ float gLp[32 * GSTR];    // 4.2 KB
    __shared__ float sL[LSEQ];
    __shared__ float qL[LSEQ];
    __shared__ float gwL[OUTC], cL[OUTC];

    // ---- phase 0: stage ----
    if (t < 128) {   // thread t owns local row il=t: 8 float4 reads, scatter to aPad
        const float4* ar4 = (const float4*)(a + (ih * 128 + t) * HID);
        const int base = (t >> 3) * ASTR + (t & 7);
        #pragma unroll
        for (int c = 0; c < 8; ++c) {
            const float4 v = ar4[c];
            const int d = c * 4;
            aPad[base + (d + 0) * 8] = v.x;
            aPad[base + (d + 1) * 8] = v.y;
            aPad[base + (d + 2) * 8] = v.z;
            aPad[base + (d + 3) * 8] = v.w;
        }
    }
    #pragma unroll
    for (int k = t; k < DE; k += 256) gLp[(k >> 5) * GSTR + (k & 31)] = gamma[k];
    sL[t] = S[t];
    qL[t] = Q[t];
    if (t < HID)  ajL[t] = a[j * HID + t];
    if (t < OUTC) { gwL[t] = GW[t]; cL[t] = C[t]; }
    __syncthreads();

    // ---- phase 1: T_j[d][o] ----
    {
        const int d = t >> 3, o0 = (t & 7) * 4;
        float4 acc = {0.f, 0.f, 0.f, 0.f};
        #pragma unroll
        for (int e = 0; e < 32; ++e) {
            const float g = gLp[d * GSTR + e] * ajL[e];
            const float4 w = *(const float4*)(W2 + (d * 32 + e) * OUTC + o0);
            acc.x = fmaf(g, w.x, acc.x);
            acc.y = fmaf(g, w.y, acc.y);
            acc.z = fmaf(g, w.z, acc.z);
            acc.w = fmaf(g, w.w, acc.w);
        }
        *(float4*)(tPad + d * TSTR + o0) = acc;
    }
    __syncthreads();

    // ---- phase 2: reg-tiled GEMM + LN epilogue ----
    // thread (iT = t>>3 in 0..31, oT = t&7): 4 local i's (iT*4..iT*4+3), 4 o's
    const int iT = t >> 3, oT = t & 7;
    const int abase = (iT >> 1) * ASTR + (iT & 1) * 4;   // chunk iT>>1, lanes (iT&1)*4..+3
    float acc[4][4];
    #pragma unroll
    for (int m = 0; m < 4; ++m)
        #pragma unroll
        for (int k = 0; k < 4; ++k) acc[m][k] = 0.f;

    #pragma unroll
    for (int d = 0; d < 32; ++d) {
        const float4 a0 = *(const float4*)(aPad + abase + d * 8);
        const float4 tf = *(const float4*)(tPad + d * TSTR + oT * 4);
        const float am[4] = {a0.x, a0.y, a0.z, a0.w};
        const float tk[4] = {tf.x, tf.y, tf.z, tf.w};
        #pragma unroll
        for (int m = 0; m < 4; ++m)
            #pragma unroll
            for (int k = 0; k < 4; ++k)
                acc[m][k] = fmaf(am[m], tk[k], acc[m][k]);
    }

    const float Sj = sL[j], Qj = qL[j];
    const float gw0 = gwL[oT * 4 + 0], gw1 = gwL[oT * 4 + 1];
    const float gw2 = gwL[oT * 4 + 2], gw3 = gwL[oT * 4 + 3];
    const float c0 = cL[oT * 4 + 0], c1 = cL[oT * 4 + 1];
    const float c2 = cL[oT * 4 + 2], c3 = cL[oT * 4 + 3];

    #pragma unroll
    for (int m = 0; m < 4; ++m) {
        const int i = ih * 128 + iT * 4 + m;
        const float Si = sL[i], Qi = qL[i];
        const float mu  = Si * Sj * (1.0f / 1024.0f);
        const float ex2 = Qi * Qj * (1.0f / 1024.0f);
        const float var = ex2 - mu * mu;
        const float r   = rsqrtf(var + EPSV);
        float4 o4;
        o4.x = fmaf(r, acc[m][0] - mu * gw0, c0);
        o4.y = fmaf(r, acc[m][1] - mu * gw1, c1);
        o4.z = fmaf(r, acc[m][2] - mu * gw2, c2);
        o4.w = fmaf(r, acc[m][3] - mu * gw3, c3);
        // 8 consecutive lanes (oT=0..7) cover one full 128 B row (i,j,:)
        *(float4*)(out + (i * LSEQ + j) * OUTC + oT * 4) = o4;
    }
}

// ---------------------------------------------------------------------------
extern "C" void kernel_launch(void* const* d_in, const int* in_sizes, int n_in,
                              void* d_out, int out_size, void* d_ws, size_t ws_size,
                              hipStream_t stream)
{
    const float* x     = (const float*)d_in[0];
    const float* W1    = (const float*)d_in[1];
    const float* b1    = (const float*)d_in[2];
    const float* gamma = (const float*)d_in[3];
    const float* beta  = (const float*)d_in[4];
    const float* W2    = (const float*)d_in[5];
    const float* b2    = (const float*)d_in[6];
    float* out = (float*)d_out;

    // workspace layout (floats)
    float* ws = (float*)d_ws;
    float* a  = ws;            // 8192
    float* S  = ws + 8192;     // 256
    float* Q  = ws + 8448;     // 256
    float* GW = ws + 8704;     // 32
    float* C  = ws + 8736;     // 32

    k1_a_stats<<<65, 256, 0, stream>>>(x, W1, b1, gamma, beta, W2, b2, a, S, Q, GW, C);
    k2_fused<<<2 * LSEQ, 256, 0, stream>>>(a, S, Q, GW, C, gamma, W2, out);
}

// Round 5
// 80.746 us; speedup vs baseline: 1.8919x; 1.0040x over previous
//
#include <hip/hip_runtime.h>

// Problem constants
#define LSEQ 256   // sequence length (i, j range)
#define INC  256   // in_channels
#define HID  32    // hidden_dim
#define OUTC 32    // out_channels
#define DE   1024  // HID*HID (LayerNorm width)
#define EPSV 1e-5f

// aPad layout (per i-half): a[i][d] at aPad[(il>>3)*ASTR + d*8 + (il&7)], il = i-128*ih.
// 260%32==4 -> phase-2 float4 reads across iT lanes hit disjoint 4-bank groups.
#define ASTR 260
// tPad: T[d][o] at tPad[d*TSTR + o]; 36%32==4 -> conflict-free across oT quads.
#define TSTR 36
// gamma/beta: gLp[d*33 + e]; bank (d+e)%32 -> phase-1 reads across d are conflict-free.
#define GSTR 33

// ---------------------------------------------------------------------------
// k1: 64 blocks, 4 rows each: a[i,d]=x[i,:]@W1[:,d]+b1[d], plus S_i, Q_i.
// (GW/C moved into k2 — k1 no longer has the serial W2-streaming tail block.)
// ---------------------------------------------------------------------------
__global__ __launch_bounds__(256) void k1_a_stats(
    const float* __restrict__ x, const float* __restrict__ W1, const float* __restrict__ b1,
    float* __restrict__ a, float* __restrict__ S, float* __restrict__ Q)
{
    __shared__ float sh0[256];
    __shared__ float shA[128];
    __shared__ float shB[128];
    const int t = threadIdx.x;
    const int b = blockIdx.x;
    const int r = t >> 6;
    const int h = (t >> 5) & 1;
    const int d = t & 31;
    const int i = b * 4 + r;
    const float* xr = x + i * INC + h * 128;
    const float* w  = W1 + (h * 128) * HID + d;
    float p0 = 0.f, p1 = 0.f;                 // 2 independent chains
    #pragma unroll 8
    for (int k = 0; k < 64; ++k) {
        p0 = fmaf(xr[2 * k],     w[(2 * k) * HID],     p0);
        p1 = fmaf(xr[2 * k + 1], w[(2 * k + 1) * HID], p1);
    }
    sh0[t] = p0 + p1;
    __syncthreads();
    if (h == 0) {
        const float tot = sh0[t] + sh0[t + 32] + b1[d];
        a[i * HID + d] = tot;
        shA[r * 32 + d] = tot;
        shB[r * 32 + d] = tot * tot;
    }
    __syncthreads();
    if (t < 4) {
        float s = 0.f, q = 0.f;
        #pragma unroll
        for (int d2 = 0; d2 < 32; ++d2) { s += shA[t * 32 + d2]; q += shB[t * 32 + d2]; }
        S[b * 4 + t] = s;
        Q[b * 4 + t] = q;
    }
}

// ---------------------------------------------------------------------------
// k2: fused per-(j, i-half) kernel. 512 blocks (2/CU), 256 threads.
//   j = blockIdx.x >> 1, ih = blockIdx.x & 1 -> i in [ih*128, ih*128+128)
//   phase 0: stage a-half (chunked-transposed), a[j,:], S, Q, gamma, beta
//   phase 1: T_j[d][o] = sum_e a[j,e]*gamma[de]*W2[de*32+o]
//            + per-thread partial GW[o]=sum_de gamma*W2, BW[o]=sum_de beta*W2
//            (W2 is streamed here anyway — GW/C come along for ~free)
//   phase 1.5: LDS-reduce GW/BW over d; C[o] = BW[o] + b2[o]
//   phase 2: reg-tiled GEMM: thread (iT=t>>3, oT=t&7) owns 4i x 4o tile
//            out[i,j,o] = r_ij*(sum_d a[i,d]*T[d,o] - mu_ij*GW[o]) + C[o]
// ---------------------------------------------------------------------------
__global__ __launch_bounds__(256) void k2_fused(
    const float* __restrict__ a, const float* __restrict__ S, const float* __restrict__ Q,
    const float* __restrict__ gamma, const float* __restrict__ beta,
    const float* __restrict__ W2, const float* __restrict__ b2,
    float* __restrict__ out)
{
    const int j  = blockIdx.x >> 1;
    const int ih = blockIdx.x & 1;
    const int t  = threadIdx.x;

    __shared__ float aPad[16 * ASTR];   // 16.6 KB: this block's 128 i-rows
    __shared__ float ajL[HID];          // a[j,:]
    __shared__ float tPad[32 * TSTR];   // 4.6 KB
    __shared__ float gLp[32 * GSTR];    // 4.2 KB gamma
    __shared__ float bLp[32 * GSTR];    // 4.2 KB beta
    __shared__ float4 redG[256];        // 4 KB GW partials
    __shared__ float4 redB[256];        // 4 KB BW partials
    __shared__ float sL[LSEQ];
    __shared__ float qL[LSEQ];
    __shared__ float gwL[OUTC], cL[OUTC];

    // ---- phase 0: stage ----
    if (t < 128) {   // thread t owns local row il=t: 8 float4 reads, scatter to aPad
        const float4* ar4 = (const float4*)(a + (ih * 128 + t) * HID);
        const int base = (t >> 3) * ASTR + (t & 7);
        #pragma unroll
        for (int c = 0; c < 8; ++c) {
            const float4 v = ar4[c];
            const int d = c * 4;
            aPad[base + (d + 0) * 8] = v.x;
            aPad[base + (d + 1) * 8] = v.y;
            aPad[base + (d + 2) * 8] = v.z;
            aPad[base + (d + 3) * 8] = v.w;
        }
    }
    #pragma unroll
    for (int k = t; k < DE; k += 256) {
        gLp[(k >> 5) * GSTR + (k & 31)] = gamma[k];
        bLp[(k >> 5) * GSTR + (k & 31)] = beta[k];
    }
    sL[t] = S[t];
    qL[t] = Q[t];
    if (t < HID)  ajL[t] = a[j * HID + t];
    __syncthreads();

    // ---- phase 1: T_j[d][o] + GW/BW partials ----
    {
        const int d = t >> 3, o0 = (t & 7) * 4;
        float4 acc = {0.f, 0.f, 0.f, 0.f};
        float4 gw4 = {0.f, 0.f, 0.f, 0.f};
        float4 bw4 = {0.f, 0.f, 0.f, 0.f};
        #pragma unroll
        for (int e = 0; e < 32; ++e) {
            const float ge = gLp[d * GSTR + e];
            const float be = bLp[d * GSTR + e];
            const float g  = ge * ajL[e];
            const float4 w = *(const float4*)(W2 + (d * 32 + e) * OUTC + o0);
            acc.x = fmaf(g, w.x, acc.x);
            acc.y = fmaf(g, w.y, acc.y);
            acc.z = fmaf(g, w.z, acc.z);
            acc.w = fmaf(g, w.w, acc.w);
            gw4.x = fmaf(ge, w.x, gw4.x);
            gw4.y = fmaf(ge, w.y, gw4.y);
            gw4.z = fmaf(ge, w.z, gw4.z);
            gw4.w = fmaf(ge, w.w, gw4.w);
            bw4.x = fmaf(be, w.x, bw4.x);
            bw4.y = fmaf(be, w.y, bw4.y);
            bw4.z = fmaf(be, w.z, bw4.z);
            bw4.w = fmaf(be, w.w, bw4.w);
        }
        *(float4*)(tPad + d * TSTR + o0) = acc;
        redG[t] = gw4;
        redB[t] = bw4;
    }
    __syncthreads();

    // ---- phase 1.5: reduce GW/BW over the 32 d-groups (8 threads, one per o-quad)
    if (t < 8) {
        float4 g  = {0.f, 0.f, 0.f, 0.f};
        float4 bb = {0.f, 0.f, 0.f, 0.f};
        #pragma unroll
        for (int d2 = 0; d2 < 32; ++d2) {
            const float4 pg = redG[d2 * 8 + t];
            const float4 pb = redB[d2 * 8 + t];
            g.x += pg.x; g.y += pg.y; g.z += pg.z; g.w += pg.w;
            bb.x += pb.x; bb.y += pb.y; bb.z += pb.z; bb.w += pb.w;
        }
        gwL[t * 4 + 0] = g.x; gwL[t * 4 + 1] = g.y;
        gwL[t * 4 + 2] = g.z; gwL[t * 4 + 3] = g.w;
        cL[t * 4 + 0] = bb.x + b2[t * 4 + 0];
        cL[t * 4 + 1] = bb.y + b2[t * 4 + 1];
        cL[t * 4 + 2] = bb.z + b2[t * 4 + 2];
        cL[t * 4 + 3] = bb.w + b2[t * 4 + 3];
    }
    __syncthreads();

    // ---- phase 2: reg-tiled GEMM + LN epilogue ----
    // thread (iT = t>>3 in 0..31, oT = t&7): 4 local i's (iT*4..iT*4+3), 4 o's
    const int iT = t >> 3, oT = t & 7;
    const int abase = (iT >> 1) * ASTR + (iT & 1) * 4;   // chunk iT>>1, lanes (iT&1)*4..+3
    float acc[4][4];
    #pragma unroll
    for (int m = 0; m < 4; ++m)
        #pragma unroll
        for (int k = 0; k < 4; ++k) acc[m][k] = 0.f;

    #pragma unroll
    for (int d = 0; d < 32; ++d) {
        const float4 a0 = *(const float4*)(aPad + abase + d * 8);
        const float4 tf = *(const float4*)(tPad + d * TSTR + oT * 4);
        const float am[4] = {a0.x, a0.y, a0.z, a0.w};
        const float tk[4] = {tf.x, tf.y, tf.z, tf.w};
        #pragma unroll
        for (int m = 0; m < 4; ++m)
            #pragma unroll
            for (int k = 0; k < 4; ++k)
                acc[m][k] = fmaf(am[m], tk[k], acc[m][k]);
    }

    const float Sj = sL[j], Qj = qL[j];
    const float gw0 = gwL[oT * 4 + 0], gw1 = gwL[oT * 4 + 1];
    const float gw2 = gwL[oT * 4 + 2], gw3 = gwL[oT * 4 + 3];
    const float c0 = cL[oT * 4 + 0], c1 = cL[oT * 4 + 1];
    const float c2 = cL[oT * 4 + 2], c3 = cL[oT * 4 + 3];

    #pragma unroll
    for (int m = 0; m < 4; ++m) {
        const int i = ih * 128 + iT * 4 + m;
        const float Si = sL[i], Qi = qL[i];
        const float mu  = Si * Sj * (1.0f / 1024.0f);
        const float ex2 = Qi * Qj * (1.0f / 1024.0f);
        const float var = ex2 - mu * mu;
        const float r   = rsqrtf(var + EPSV);
        float4 o4;
        o4.x = fmaf(r, acc[m][0] - mu * gw0, c0);
        o4.y = fmaf(r, acc[m][1] - mu * gw1, c1);
        o4.z = fmaf(r, acc[m][2] - mu * gw2, c2);
        o4.w = fmaf(r, acc[m][3] - mu * gw3, c3);
        // 8 consecutive lanes (oT=0..7) cover one full 128 B row (i,j,:)
        *(float4*)(out + (i * LSEQ + j) * OUTC + oT * 4) = o4;
    }
}

// ---------------------------------------------------------------------------
extern "C" void kernel_launch(void* const* d_in, const int* in_sizes, int n_in,
                              void* d_out, int out_size, void* d_ws, size_t ws_size,
                              hipStream_t stream)
{
    const float* x     = (const float*)d_in[0];
    const float* W1    = (const float*)d_in[1];
    const float* b1    = (const float*)d_in[2];
    const float* gamma = (const float*)d_in[3];
    const float* beta  = (const float*)d_in[4];
    const float* W2    = (const float*)d_in[5];
    const float* b2    = (const float*)d_in[6];
    float* out = (float*)d_out;

    // workspace layout (floats)
    float* ws = (float*)d_ws;
    float* a  = ws;            // 8192
    float* S  = ws + 8192;     // 256
    float* Q  = ws + 8448;     // 256

    k1_a_stats<<<64, 256, 0, stream>>>(x, W1, b1, a, S, Q);
    k2_fused<<<2 * LSEQ, 256, 0, stream>>>(a, S, Q, gamma, beta, W2, b2, out);
}